// Round 17
// baseline (92.114 us; speedup 1.0000x reference)
//
#include <hip/hip_runtime.h>
#include <hip/hip_bf16.h>

#define HWN 9216              // 96*96
#define PLN (64 * HWN)        // one frame's feature plane (C=64)
#define SLDE 584              // LDS row stride (bf16 elems)

typedef __attribute__((ext_vector_type(8))) short bf16x8;
typedef __attribute__((ext_vector_type(4))) float f32x4;

// Native bf16 convert (RNE) — lets the compiler pick/fuse v_cvt_pk_bf16_f32.
__device__ __forceinline__ unsigned short f2bf(float v) {
    __hip_bfloat16 h = __float2bfloat16(v);
    return __builtin_bit_cast(unsigned short, h);
}
__device__ __forceinline__ float bf2f(unsigned short b) {
    union { unsigned u; float f; } cv; cv.u = ((unsigned)b) << 16;
    return cv.f;
}

// ---------------------------------------------------------------------------
// y<5 : transpose x[t][c][p] f32 -> xt[t][p][64c] bf16 (+ center copy to out)
// y==5: weight reorders to K' = g*72 + k*8 + cg, bf16:
//       wbf[64][576] <- w_dcn; wcbf[2][144][576] <- w_off (slab0 neig, 1 ctr)
// ---------------------------------------------------------------------------
__global__ __launch_bounds__(256) void xprep_kernel(
    const float* __restrict__ x, const float* __restrict__ w_dcn,
    const float* __restrict__ w_off, unsigned short* __restrict__ xt,
    unsigned short* __restrict__ wbf, unsigned short* __restrict__ wcbf,
    float* __restrict__ out)
{
    const int t = blockIdx.y;
    const int tid = threadIdx.x;
    if (t == 5) {   // weight prep
        for (int idx = blockIdx.x * 256 + tid; idx < 64 * 576 + 2 * 144 * 576;
             idx += 144 * 256) {
            if (idx < 64 * 576) {
                int o = idx / 576, c = idx % 576;
                int g = c / 72, rem = c % 72, k = rem >> 3, cg = rem & 7;
                wbf[idx] = f2bf(w_dcn[o * 576 + (g * 8 + cg) * 9 + k]);
            } else {
                int i2 = idx - 64 * 576;
                int s = i2 / (144 * 576);
                int o = (i2 / 576) % 144;
                int kk = i2 % 576;
                int g = kk / 72, rem = kk % 72, k = rem >> 3, cg = rem & 7;
                wcbf[i2] = f2bf(w_off[(size_t)o * 1152
                                      + (size_t)(s * 64 + g * 8 + cg) * 9 + k]);
            }
        }
        return;
    }
    const int p0 = blockIdx.x * 64;
    __shared__ unsigned short tile[64][72];
    const float* in = x + (size_t)t * PLN;
    const bool isC = (t == 2);
    for (int idx = tid; idx < 4096; idx += 256) {
        int c = idx >> 6, p = idx & 63;
        float v = in[(size_t)c * HWN + p0 + p];
        tile[p][c] = f2bf(v);
        if (isC) out[(size_t)2 * PLN + (size_t)c * HWN + p0 + p] = v;
    }
    __syncthreads();
    unsigned short* xo = xt + ((size_t)t * HWN + p0) * 64;
    for (int task = tid; task < 512; task += 256) {
        int p = task >> 3, cb = task & 7;
        *reinterpret_cast<bf16x8*>(xo + p * 64 + cb * 8) =
            *reinterpret_cast<const bf16x8*>(&tile[p][cb * 8]);
    }
}

// ---------------------------------------------------------------------------
// Center-slab conv: wsC[144][9216] (bf16) = W_ctr[144x576] * im2col(center).
// 576 thr (9 waves), 32-px tile, grid 288. Batched 4-granule staging.
// ---------------------------------------------------------------------------
__global__ __launch_bounds__(576, 2) void conv_center_kernel(
    const unsigned short* __restrict__ xt,
    const unsigned short* __restrict__ wcbf,
    unsigned short* __restrict__ wsC)
{
    const int p0 = blockIdx.x * 32;
    const int tid = threadIdx.x;
    const int w = tid >> 6, l = tid & 63;
    const int lr = l & 15, lg = l >> 4;

    __shared__ unsigned short smp[32 * SLDE];

    {
        const unsigned short* xb = xt + (size_t)2 * HWN * 64;
        const bf16x8 bz = {0,0,0,0,0,0,0,0};
        bf16x8 stg[4]; int dst[4];
        #pragma unroll
        for (int i = 0; i < 4; ++i) {
            const int tsk = i * 576 + tid;          // 0..2303
            const int g = tsk & 7, pl = (tsk >> 3) & 31, k = tsk >> 8;
            const int p = p0 + pl;
            const int y = p / 96, xx = p - y * 96;
            const int r = k / 3, d = k - 3 * (k / 3);
            const int yy = y + r - 1, xw = xx + d - 1;
            const bool valid = (yy >= 0) & (yy < 96) & (xw >= 0) & (xw < 96);
            const int lin = min(max(yy, 0), 95) * 96 + min(max(xw, 0), 95);
            bf16x8 v = *reinterpret_cast<const bf16x8*>(xb + (size_t)lin * 64 + g * 8);
            stg[i] = valid ? v : bz;
            dst[i] = pl * SLDE + g * 72 + k * 8;
        }
        #pragma unroll
        for (int i = 0; i < 4; ++i)
            *reinterpret_cast<bf16x8*>(smp + dst[i]) = stg[i];
    }
    __syncthreads();

    const unsigned short* wp = wcbf + (size_t)1 * 144 * 576
                               + (size_t)(w * 16 + lr) * 576 + lg * 8;
    bf16x8 afr[18];
    #pragma unroll
    for (int ss = 0; ss < 18; ++ss)
        afr[ss] = *reinterpret_cast<const bf16x8*>(wp + ss * 32);

    f32x4 acc[2] = {{0,0,0,0},{0,0,0,0}};
    #pragma unroll
    for (int pt = 0; pt < 2; ++pt) {
        const unsigned short* brow = smp + (pt * 16 + lr) * SLDE + lg * 8;
        #pragma unroll
        for (int ss = 0; ss < 18; ++ss) {
            bf16x8 b = *reinterpret_cast<const bf16x8*>(brow + ss * 32);
            acc[pt] = __builtin_amdgcn_mfma_f32_16x16x32_bf16(afr[ss], b, acc[pt], 0, 0, 0);
        }
    }
    #pragma unroll
    for (int pt = 0; pt < 2; ++pt) {
        const int px = p0 + pt * 16 + lr;
        #pragma unroll
        for (int r = 0; r < 4; ++r) {
            const int o = w * 16 + lg * 4 + r;   // C/D: row=(lane>>4)*4+r, col=lane&15
            wsC[(size_t)o * HWN + px] = f2bf(acc[pt][r]);
        }
    }
}

// ---------------------------------------------------------------------------
// Neighbor-slab conv: ofs[f] (bf16) = W_neig * im2col(frame f) + wsC + b_off.
// 576 thr (9 waves), 64-px tile, grid (144,4). Batched 8-granule staging,
// single barrier per block. K=576.
// ---------------------------------------------------------------------------
__global__ __launch_bounds__(576, 2) void conv_neig_kernel(
    const unsigned short* __restrict__ xt,
    const unsigned short* __restrict__ wcbf,
    const float* __restrict__ b_off,
    const unsigned short* __restrict__ wsC,
    unsigned short* __restrict__ ofs)
{
    const int f = blockIdx.y;
    const int t = f < 2 ? f : f + 1;
    const int p0 = blockIdx.x * 64;
    const int tid = threadIdx.x;
    const int w = tid >> 6, l = tid & 63;
    const int lr = l & 15, lg = l >> 4;

    __shared__ unsigned short smp[64 * SLDE];

    {
        const unsigned short* xb = xt + (size_t)t * HWN * 64;
        const bf16x8 bz = {0,0,0,0,0,0,0,0};
        bf16x8 stg[8]; int dst[8];
        #pragma unroll
        for (int i = 0; i < 8; ++i) {
            const int tsk = i * 576 + tid;          // 0..4607
            const int g = tsk & 7, pl = (tsk >> 3) & 63, k = tsk >> 9;
            const int p = p0 + pl;
            const int y = p / 96, xx = p - y * 96;
            const int r = k / 3, d = k - 3 * (k / 3);
            const int yy = y + r - 1, xw = xx + d - 1;
            const bool valid = (yy >= 0) & (yy < 96) & (xw >= 0) & (xw < 96);
            const int lin = min(max(yy, 0), 95) * 96 + min(max(xw, 0), 95);
            bf16x8 v = *reinterpret_cast<const bf16x8*>(xb + (size_t)lin * 64 + g * 8);
            stg[i] = valid ? v : bz;
            dst[i] = pl * SLDE + g * 72 + k * 8;
        }
        #pragma unroll
        for (int i = 0; i < 8; ++i)
            *reinterpret_cast<bf16x8*>(smp + dst[i]) = stg[i];
    }
    __syncthreads();

    const unsigned short* wp = wcbf + (size_t)(w * 16 + lr) * 576 + lg * 8;
    bf16x8 afr[18];
    #pragma unroll
    for (int ss = 0; ss < 18; ++ss)
        afr[ss] = *reinterpret_cast<const bf16x8*>(wp + ss * 32);

    f32x4 acc[4] = {{0,0,0,0},{0,0,0,0},{0,0,0,0},{0,0,0,0}};
    #pragma unroll
    for (int pt = 0; pt < 4; ++pt) {
        const unsigned short* brow = smp + (pt * 16 + lr) * SLDE + lg * 8;
        #pragma unroll
        for (int ss = 0; ss < 18; ++ss) {
            bf16x8 b = *reinterpret_cast<const bf16x8*>(brow + ss * 32);
            acc[pt] = __builtin_amdgcn_mfma_f32_16x16x32_bf16(afr[ss], b, acc[pt], 0, 0, 0);
        }
    }

    unsigned short* of = ofs + (size_t)f * 144 * HWN;
    #pragma unroll
    for (int pt = 0; pt < 4; ++pt) {
        const int px = p0 + pt * 16 + lr;
        #pragma unroll
        for (int r = 0; r < 4; ++r) {
            const int o = w * 16 + lg * 4 + r;   // C/D: row=(lane>>4)*4+r, col=lane&15
            of[(size_t)o * HWN + px] =
                f2bf(acc[pt][r] + bf2f(wsC[(size_t)o * HWN + px]) + b_off[o]);
        }
    }
}

// ---------------------------------------------------------------------------
// Deform: LDS-staged sampling + MFMA projection. 256 thr (4 waves),
// 32-px tile, grid (288,4). Depth-2 tap pipeline in phase 1. bf16 offsets.
// ---------------------------------------------------------------------------
__global__ __launch_bounds__(256, 4) void deform_kernel(
    const unsigned short* __restrict__ xt,
    const unsigned short* __restrict__ ofs,
    const unsigned short* __restrict__ wbf,
    const float* __restrict__ b_dcn,
    float* __restrict__ out)
{
    const int f = blockIdx.y;
    const int t = f < 2 ? f : f + 1;
    const int p0 = blockIdx.x * 32;
    const int tid = threadIdx.x;

    __shared__ unsigned short smp[32 * SLDE];   // [pix][K'], K' = g*72+k*8+cg

    {
        const int g = tid >> 5, pl = tid & 31;
        const int p = p0 + pl;
        const int y = p / 96, xx = p - y * 96;
        const unsigned short* xf = xt + (size_t)t * HWN * 64 + g * 8;
        const unsigned short* ob = ofs + (size_t)f * 144 * HWN + (size_t)g * 18 * HWN + p;
        float dy[9], dx[9];
        #pragma unroll
        for (int k = 0; k < 9; ++k) {
            dy[k] = bf2f(ob[(size_t)(2 * k) * HWN]);
            dx[k] = bf2f(ob[(size_t)(2 * k + 1) * HWN]);
        }
        unsigned short* srow = smp + pl * SLDE + g * 72;

        bf16x8 cc[2][4];
        float  ww[2][4];
        auto prep = [&](int k, int buf) {
            const int r = k / 3, d = k - 3 * (k / 3);
            const float ys = (float)(y + r - 1) + dy[k];
            const float xs = (float)(xx + d - 1) + dx[k];
            const float y0f = floorf(ys), x0f = floorf(xs);
            const float wy = ys - y0f, wx = xs - x0f;
            const int y0 = (int)y0f, x0 = (int)x0f;
            const int y1 = y0 + 1, x1 = x0 + 1;
            const bool vy0 = (y0 >= 0) & (y0 < 96);
            const bool vy1 = (y1 >= 0) & (y1 < 96);
            const bool vx0 = (x0 >= 0) & (x0 < 96);
            const bool vx1 = (x1 >= 0) & (x1 < 96);
            const int yc0 = min(max(y0, 0), 95), yc1 = min(max(y1, 0), 95);
            const int xc0 = min(max(x0, 0), 95), xc1 = min(max(x1, 0), 95);
            ww[buf][0] = (vy0 & vx0) ? (1.f - wy) * (1.f - wx) : 0.f;
            ww[buf][1] = (vy0 & vx1) ? (1.f - wy) * wx : 0.f;
            ww[buf][2] = (vy1 & vx0) ? wy * (1.f - wx) : 0.f;
            ww[buf][3] = (vy1 & vx1) ? wy * wx : 0.f;
            cc[buf][0] = *reinterpret_cast<const bf16x8*>(xf + (size_t)(yc0 * 96 + xc0) * 64);
            cc[buf][1] = *reinterpret_cast<const bf16x8*>(xf + (size_t)(yc0 * 96 + xc1) * 64);
            cc[buf][2] = *reinterpret_cast<const bf16x8*>(xf + (size_t)(yc1 * 96 + xc0) * 64);
            cc[buf][3] = *reinterpret_cast<const bf16x8*>(xf + (size_t)(yc1 * 96 + xc1) * 64);
        };

        prep(0, 0);
        #pragma unroll
        for (int k = 0; k < 9; ++k) {
            if (k < 8) prep(k + 1, (k + 1) & 1);     // prefetch next tap
            const int b = k & 1;
            bf16x8 pk;
            #pragma unroll
            for (int ch = 0; ch < 8; ++ch) {
                float v = ww[b][0] * bf2f((unsigned short)cc[b][0][ch]);
                v = fmaf(ww[b][1], bf2f((unsigned short)cc[b][1][ch]), v);
                v = fmaf(ww[b][2], bf2f((unsigned short)cc[b][2][ch]), v);
                v = fmaf(ww[b][3], bf2f((unsigned short)cc[b][3][ch]), v);
                pk[ch] = (short)f2bf(v);
            }
            *reinterpret_cast<bf16x8*>(srow + k * 8) = pk;   // 16B aligned
        }
    }
    __syncthreads();

    const int w = tid >> 6;
    const int l = tid & 63;
    const int o0 = w * 16;
    const int lr = l & 15, lg = l >> 4;

    bf16x8 afr[18];
    const unsigned short* wrow = wbf + (size_t)(o0 + lr) * 576 + lg * 8;
    #pragma unroll
    for (int s = 0; s < 18; ++s)
        afr[s] = *reinterpret_cast<const bf16x8*>(wrow + s * 32);

    f32x4 acc0 = {0.f, 0.f, 0.f, 0.f}, acc1 = {0.f, 0.f, 0.f, 0.f};
    const unsigned short* brow0 = smp + lr * SLDE + lg * 8;
    const unsigned short* brow1 = brow0 + 16 * SLDE;
    #pragma unroll
    for (int s = 0; s < 18; ++s) {
        bf16x8 b0 = *reinterpret_cast<const bf16x8*>(brow0 + s * 32);
        bf16x8 b1 = *reinterpret_cast<const bf16x8*>(brow1 + s * 32);
        acc0 = __builtin_amdgcn_mfma_f32_16x16x32_bf16(afr[s], b0, acc0, 0, 0, 0);
        acc1 = __builtin_amdgcn_mfma_f32_16x16x32_bf16(afr[s], b1, acc1, 0, 0, 0);
    }

    float* op = out + (size_t)t * PLN + p0;
    #pragma unroll
    for (int r = 0; r < 4; ++r) {
        const int o = o0 + lg * 4 + r;              // C/D: row=(lane>>4)*4+r
        const float bb = b_dcn[o];
        op[(size_t)o * HWN + lr] = acc0[r] + bb;              // col = lane&15
        op[(size_t)o * HWN + 16 + lr] = acc1[r] + bb;
    }
}

extern "C" void kernel_launch(void* const* d_in, const int* in_sizes, int n_in,
                              void* d_out, int out_size, void* d_ws, size_t ws_size,
                              hipStream_t stream) {
    const float* x     = (const float*)d_in[0];
    const float* w_off = (const float*)d_in[1];
    const float* b_off = (const float*)d_in[2];
    const float* w_dcn = (const float*)d_in[3];
    const float* b_dcn = (const float*)d_in[4];
    float* out = (float*)d_out;

    unsigned short* ofs  = (unsigned short*)d_ws;              // [4][144][9216] bf16, 10.6 MB
    unsigned short* xt   = ofs + (size_t)4 * 144 * HWN;        // [5][9216][64] bf16, 5.9 MB
    unsigned short* wbf  = xt + (size_t)5 * HWN * 64;          // [64][576] bf16
    unsigned short* wcbf = wbf + (size_t)64 * 576;             // [2][144][576] bf16
    unsigned short* wsC  = wcbf + (size_t)2 * 144 * 576;       // [144][9216] bf16, 2.65 MB
    // ws total ~19.6 MB

    // feat transpose + center passthrough + weight reorders (y==5 slice)
    xprep_kernel<<<dim3(144, 6), 256, 0, stream>>>(x, w_dcn, w_off, xt, wbf, wcbf, out);

    // center-slab conv (frame-invariant, computed once) -> wsC (bf16)
    conv_center_kernel<<<288, 576, 0, stream>>>(xt, wcbf, wsC);

    // neighbor-slab conv + wsC + bias -> ofs (bf16) for 4 frames
    conv_neig_kernel<<<dim3(144, 4), 576, 0, stream>>>(xt, wcbf, b_off, wsC, ofs);

    // deformable sampling + projection
    deform_kernel<<<dim3(288, 4), 256, 0, stream>>>(xt, ofs, wbf, b_dcn, out);
}

// Round 18
// 82.303 us; speedup vs baseline: 1.1192x; 1.1192x over previous
//
#include <hip/hip_runtime.h>
#include <hip/hip_bf16.h>

#define HWN 9216              // 96*96
#define PLN (64 * HWN)        // one frame's feature plane (C=64)
#define SLDE 584              // LDS row stride (bf16 elems)

typedef __attribute__((ext_vector_type(8))) short bf16x8;
typedef __attribute__((ext_vector_type(4))) float f32x4;

// Native bf16 convert (RNE) — lets the compiler pick/fuse v_cvt_pk_bf16_f32.
__device__ __forceinline__ unsigned short f2bf(float v) {
    __hip_bfloat16 h = __float2bfloat16(v);
    return __builtin_bit_cast(unsigned short, h);
}
__device__ __forceinline__ float bf2f(unsigned short b) {
    union { unsigned u; float f; } cv; cv.u = ((unsigned)b) << 16;
    return cv.f;
}

// ---------------------------------------------------------------------------
// y<5 : transpose x[t][c][p] f32 -> xt[t][p][64c] bf16 (+ center copy to out)
// y==5: weight reorders to K' = g*72 + k*8 + cg, bf16:
//       wbf[64][576] <- w_dcn; wcbf[2][144][576] <- w_off (slab0 neig, 1 ctr)
// ---------------------------------------------------------------------------
__global__ __launch_bounds__(256) void xprep_kernel(
    const float* __restrict__ x, const float* __restrict__ w_dcn,
    const float* __restrict__ w_off, unsigned short* __restrict__ xt,
    unsigned short* __restrict__ wbf, unsigned short* __restrict__ wcbf,
    float* __restrict__ out)
{
    const int t = blockIdx.y;
    const int tid = threadIdx.x;
    if (t == 5) {   // weight prep
        for (int idx = blockIdx.x * 256 + tid; idx < 64 * 576 + 2 * 144 * 576;
             idx += 144 * 256) {
            if (idx < 64 * 576) {
                int o = idx / 576, c = idx % 576;
                int g = c / 72, rem = c % 72, k = rem >> 3, cg = rem & 7;
                wbf[idx] = f2bf(w_dcn[o * 576 + (g * 8 + cg) * 9 + k]);
            } else {
                int i2 = idx - 64 * 576;
                int s = i2 / (144 * 576);
                int o = (i2 / 576) % 144;
                int kk = i2 % 576;
                int g = kk / 72, rem = kk % 72, k = rem >> 3, cg = rem & 7;
                wcbf[i2] = f2bf(w_off[(size_t)o * 1152
                                      + (size_t)(s * 64 + g * 8 + cg) * 9 + k]);
            }
        }
        return;
    }
    const int p0 = blockIdx.x * 64;
    __shared__ unsigned short tile[64][72];
    const float* in = x + (size_t)t * PLN;
    const bool isC = (t == 2);
    for (int idx = tid; idx < 4096; idx += 256) {
        int c = idx >> 6, p = idx & 63;
        float v = in[(size_t)c * HWN + p0 + p];
        tile[p][c] = f2bf(v);
        if (isC) out[(size_t)2 * PLN + (size_t)c * HWN + p0 + p] = v;
    }
    __syncthreads();
    unsigned short* xo = xt + ((size_t)t * HWN + p0) * 64;
    for (int task = tid; task < 512; task += 256) {
        int p = task >> 3, cb = task & 7;
        *reinterpret_cast<bf16x8*>(xo + p * 64 + cb * 8) =
            *reinterpret_cast<const bf16x8*>(&tile[p][cb * 8]);
    }
}

// ---------------------------------------------------------------------------
// Center-slab conv: wsC[144][9216] = W_ctr[144x576] * im2col(center).
// 576 thr (9 waves), 32-px tile, grid 288. Batched 4-granule staging.
// ---------------------------------------------------------------------------
__global__ __launch_bounds__(576, 2) void conv_center_kernel(
    const unsigned short* __restrict__ xt,
    const unsigned short* __restrict__ wcbf,
    float* __restrict__ wsC)
{
    const int p0 = blockIdx.x * 32;
    const int tid = threadIdx.x;
    const int w = tid >> 6, l = tid & 63;
    const int lr = l & 15, lg = l >> 4;

    __shared__ unsigned short smp[32 * SLDE];

    {
        const unsigned short* xb = xt + (size_t)2 * HWN * 64;
        const bf16x8 bz = {0,0,0,0,0,0,0,0};
        bf16x8 stg[4]; int dst[4];
        #pragma unroll
        for (int i = 0; i < 4; ++i) {
            const int tsk = i * 576 + tid;          // 0..2303
            const int g = tsk & 7, pl = (tsk >> 3) & 31, k = tsk >> 8;
            const int p = p0 + pl;
            const int y = p / 96, xx = p - y * 96;
            const int r = k / 3, d = k - 3 * (k / 3);
            const int yy = y + r - 1, xw = xx + d - 1;
            const bool valid = (yy >= 0) & (yy < 96) & (xw >= 0) & (xw < 96);
            const int lin = min(max(yy, 0), 95) * 96 + min(max(xw, 0), 95);
            bf16x8 v = *reinterpret_cast<const bf16x8*>(xb + (size_t)lin * 64 + g * 8);
            stg[i] = valid ? v : bz;
            dst[i] = pl * SLDE + g * 72 + k * 8;
        }
        #pragma unroll
        for (int i = 0; i < 4; ++i)
            *reinterpret_cast<bf16x8*>(smp + dst[i]) = stg[i];
    }
    __syncthreads();

    const unsigned short* wp = wcbf + (size_t)1 * 144 * 576
                               + (size_t)(w * 16 + lr) * 576 + lg * 8;
    bf16x8 afr[18];
    #pragma unroll
    for (int ss = 0; ss < 18; ++ss)
        afr[ss] = *reinterpret_cast<const bf16x8*>(wp + ss * 32);

    f32x4 acc[2] = {{0,0,0,0},{0,0,0,0}};
    #pragma unroll
    for (int pt = 0; pt < 2; ++pt) {
        const unsigned short* brow = smp + (pt * 16 + lr) * SLDE + lg * 8;
        #pragma unroll
        for (int ss = 0; ss < 18; ++ss) {
            bf16x8 b = *reinterpret_cast<const bf16x8*>(brow + ss * 32);
            acc[pt] = __builtin_amdgcn_mfma_f32_16x16x32_bf16(afr[ss], b, acc[pt], 0, 0, 0);
        }
    }
    #pragma unroll
    for (int pt = 0; pt < 2; ++pt) {
        const int px = p0 + pt * 16 + lr;
        #pragma unroll
        for (int r = 0; r < 4; ++r) {
            const int o = w * 16 + lg * 4 + r;   // C/D: row=(lane>>4)*4+r, col=lane&15
            wsC[(size_t)o * HWN + px] = acc[pt][r];
        }
    }
}

// ---------------------------------------------------------------------------
// Neighbor-slab conv: ofs[f] = W_neig * im2col(frame f) + wsC + b_off.
// 576 thr (9 waves), 64-px tile, grid (144,4). Batched 8-granule staging,
// single barrier per block. K=576. Epilogue inputs (wsC, b_off) PREFETCHED
// at kernel top — their ~16-line latency chain drains under staging+MFMA.
// ---------------------------------------------------------------------------
__global__ __launch_bounds__(576, 2) void conv_neig_kernel(
    const unsigned short* __restrict__ xt,
    const unsigned short* __restrict__ wcbf,
    const float* __restrict__ b_off,
    const float* __restrict__ wsC,
    float* __restrict__ ofs)
{
    const int f = blockIdx.y;
    const int t = f < 2 ? f : f + 1;
    const int p0 = blockIdx.x * 64;
    const int tid = threadIdx.x;
    const int w = tid >> 6, l = tid & 63;
    const int lr = l & 15, lg = l >> 4;

    __shared__ unsigned short smp[64 * SLDE];

    // ---- epilogue-input prefetch (independent of all kernel compute) ----
    float wpre[4][4], bpre[4];
    #pragma unroll
    for (int r = 0; r < 4; ++r) {
        const int o = w * 16 + lg * 4 + r;
        bpre[r] = b_off[o];
        #pragma unroll
        for (int pt = 0; pt < 4; ++pt)
            wpre[pt][r] = wsC[(size_t)o * HWN + p0 + pt * 16 + lr];
    }

    {
        const unsigned short* xb = xt + (size_t)t * HWN * 64;
        const bf16x8 bz = {0,0,0,0,0,0,0,0};
        bf16x8 stg[8]; int dst[8];
        #pragma unroll
        for (int i = 0; i < 8; ++i) {
            const int tsk = i * 576 + tid;          // 0..4607
            const int g = tsk & 7, pl = (tsk >> 3) & 63, k = tsk >> 9;
            const int p = p0 + pl;
            const int y = p / 96, xx = p - y * 96;
            const int r = k / 3, d = k - 3 * (k / 3);
            const int yy = y + r - 1, xw = xx + d - 1;
            const bool valid = (yy >= 0) & (yy < 96) & (xw >= 0) & (xw < 96);
            const int lin = min(max(yy, 0), 95) * 96 + min(max(xw, 0), 95);
            bf16x8 v = *reinterpret_cast<const bf16x8*>(xb + (size_t)lin * 64 + g * 8);
            stg[i] = valid ? v : bz;
            dst[i] = pl * SLDE + g * 72 + k * 8;
        }
        #pragma unroll
        for (int i = 0; i < 8; ++i)
            *reinterpret_cast<bf16x8*>(smp + dst[i]) = stg[i];
    }
    __syncthreads();

    const unsigned short* wp = wcbf + (size_t)(w * 16 + lr) * 576 + lg * 8;
    bf16x8 afr[18];
    #pragma unroll
    for (int ss = 0; ss < 18; ++ss)
        afr[ss] = *reinterpret_cast<const bf16x8*>(wp + ss * 32);

    f32x4 acc[4] = {{0,0,0,0},{0,0,0,0},{0,0,0,0},{0,0,0,0}};
    #pragma unroll
    for (int pt = 0; pt < 4; ++pt) {
        const unsigned short* brow = smp + (pt * 16 + lr) * SLDE + lg * 8;
        #pragma unroll
        for (int ss = 0; ss < 18; ++ss) {
            bf16x8 b = *reinterpret_cast<const bf16x8*>(brow + ss * 32);
            acc[pt] = __builtin_amdgcn_mfma_f32_16x16x32_bf16(afr[ss], b, acc[pt], 0, 0, 0);
        }
    }

    float* of = ofs + (size_t)f * 144 * HWN;
    #pragma unroll
    for (int pt = 0; pt < 4; ++pt) {
        const int px = p0 + pt * 16 + lr;
        #pragma unroll
        for (int r = 0; r < 4; ++r) {
            const int o = w * 16 + lg * 4 + r;   // C/D: row=(lane>>4)*4+r, col=lane&15
            of[(size_t)o * HWN + px] = acc[pt][r] + wpre[pt][r] + bpre[r];
        }
    }
}

// ---------------------------------------------------------------------------
// Deform: LDS-staged sampling + MFMA projection. 256 thr (4 waves),
// 32-px tile, grid (288,4). Depth-2 tap pipeline in phase 1.
// b_dcn prefetched at top.
// ---------------------------------------------------------------------------
__global__ __launch_bounds__(256, 4) void deform_kernel(
    const unsigned short* __restrict__ xt,
    const float* __restrict__ ofs,
    const unsigned short* __restrict__ wbf,
    const float* __restrict__ b_dcn,
    float* __restrict__ out)
{
    const int f = blockIdx.y;
    const int t = f < 2 ? f : f + 1;
    const int p0 = blockIdx.x * 32;
    const int tid = threadIdx.x;

    __shared__ unsigned short smp[32 * SLDE];   // [pix][K'], K' = g*72+k*8+cg

    // ---- epilogue-input prefetch ----
    float bpre[4];
    {
        const int o0p = (tid >> 6) * 16 + ((tid & 63) >> 4) * 4;
        #pragma unroll
        for (int r = 0; r < 4; ++r) bpre[r] = b_dcn[o0p + r];
    }

    {
        const int g = tid >> 5, pl = tid & 31;
        const int p = p0 + pl;
        const int y = p / 96, xx = p - y * 96;
        const unsigned short* xf = xt + (size_t)t * HWN * 64 + g * 8;
        const float* ob = ofs + (size_t)f * 144 * HWN + (size_t)g * 18 * HWN + p;
        float dy[9], dx[9];
        #pragma unroll
        for (int k = 0; k < 9; ++k) {
            dy[k] = ob[(size_t)(2 * k) * HWN];
            dx[k] = ob[(size_t)(2 * k + 1) * HWN];
        }
        unsigned short* srow = smp + pl * SLDE + g * 72;

        bf16x8 cc[2][4];
        float  ww[2][4];
        auto prep = [&](int k, int buf) {
            const int r = k / 3, d = k - 3 * (k / 3);
            const float ys = (float)(y + r - 1) + dy[k];
            const float xs = (float)(xx + d - 1) + dx[k];
            const float y0f = floorf(ys), x0f = floorf(xs);
            const float wy = ys - y0f, wx = xs - x0f;
            const int y0 = (int)y0f, x0 = (int)x0f;
            const int y1 = y0 + 1, x1 = x0 + 1;
            const bool vy0 = (y0 >= 0) & (y0 < 96);
            const bool vy1 = (y1 >= 0) & (y1 < 96);
            const bool vx0 = (x0 >= 0) & (x0 < 96);
            const bool vx1 = (x1 >= 0) & (x1 < 96);
            const int yc0 = min(max(y0, 0), 95), yc1 = min(max(y1, 0), 95);
            const int xc0 = min(max(x0, 0), 95), xc1 = min(max(x1, 0), 95);
            ww[buf][0] = (vy0 & vx0) ? (1.f - wy) * (1.f - wx) : 0.f;
            ww[buf][1] = (vy0 & vx1) ? (1.f - wy) * wx : 0.f;
            ww[buf][2] = (vy1 & vx0) ? wy * (1.f - wx) : 0.f;
            ww[buf][3] = (vy1 & vx1) ? wy * wx : 0.f;
            cc[buf][0] = *reinterpret_cast<const bf16x8*>(xf + (size_t)(yc0 * 96 + xc0) * 64);
            cc[buf][1] = *reinterpret_cast<const bf16x8*>(xf + (size_t)(yc0 * 96 + xc1) * 64);
            cc[buf][2] = *reinterpret_cast<const bf16x8*>(xf + (size_t)(yc1 * 96 + xc0) * 64);
            cc[buf][3] = *reinterpret_cast<const bf16x8*>(xf + (size_t)(yc1 * 96 + xc1) * 64);
        };

        prep(0, 0);
        #pragma unroll
        for (int k = 0; k < 9; ++k) {
            if (k < 8) prep(k + 1, (k + 1) & 1);     // prefetch next tap
            const int b = k & 1;
            bf16x8 pk;
            #pragma unroll
            for (int ch = 0; ch < 8; ++ch) {
                float v = ww[b][0] * bf2f((unsigned short)cc[b][0][ch]);
                v = fmaf(ww[b][1], bf2f((unsigned short)cc[b][1][ch]), v);
                v = fmaf(ww[b][2], bf2f((unsigned short)cc[b][2][ch]), v);
                v = fmaf(ww[b][3], bf2f((unsigned short)cc[b][3][ch]), v);
                pk[ch] = (short)f2bf(v);
            }
            *reinterpret_cast<bf16x8*>(srow + k * 8) = pk;   // 16B aligned
        }
    }
    __syncthreads();

    const int w = tid >> 6;
    const int l = tid & 63;
    const int o0 = w * 16;
    const int lr = l & 15, lg = l >> 4;

    bf16x8 afr[18];
    const unsigned short* wrow = wbf + (size_t)(o0 + lr) * 576 + lg * 8;
    #pragma unroll
    for (int s = 0; s < 18; ++s)
        afr[s] = *reinterpret_cast<const bf16x8*>(wrow + s * 32);

    f32x4 acc0 = {0.f, 0.f, 0.f, 0.f}, acc1 = {0.f, 0.f, 0.f, 0.f};
    const unsigned short* brow0 = smp + lr * SLDE + lg * 8;
    const unsigned short* brow1 = brow0 + 16 * SLDE;
    #pragma unroll
    for (int s = 0; s < 18; ++s) {
        bf16x8 b0 = *reinterpret_cast<const bf16x8*>(brow0 + s * 32);
        bf16x8 b1 = *reinterpret_cast<const bf16x8*>(brow1 + s * 32);
        acc0 = __builtin_amdgcn_mfma_f32_16x16x32_bf16(afr[s], b0, acc0, 0, 0, 0);
        acc1 = __builtin_amdgcn_mfma_f32_16x16x32_bf16(afr[s], b1, acc1, 0, 0, 0);
    }

    float* op = out + (size_t)t * PLN + p0;
    #pragma unroll
    for (int r = 0; r < 4; ++r) {
        const int o = o0 + lg * 4 + r;              // C/D: row=(lane>>4)*4+r
        op[(size_t)o * HWN + lr] = acc0[r] + bpre[r];         // col = lane&15
        op[(size_t)o * HWN + 16 + lr] = acc1[r] + bpre[r];
    }
}

extern "C" void kernel_launch(void* const* d_in, const int* in_sizes, int n_in,
                              void* d_out, int out_size, void* d_ws, size_t ws_size,
                              hipStream_t stream) {
    const float* x     = (const float*)d_in[0];
    const float* w_off = (const float*)d_in[1];
    const float* b_off = (const float*)d_in[2];
    const float* w_dcn = (const float*)d_in[3];
    const float* b_dcn = (const float*)d_in[4];
    float* out = (float*)d_out;

    float* ofs          = (float*)d_ws;                        // [4][144][9216] f32, 21.2 MB
    unsigned short* xt  = (unsigned short*)(ofs + (size_t)4 * 144 * HWN); // [5][9216][64] bf16, 5.9 MB
    unsigned short* wbf = xt + (size_t)5 * HWN * 64;           // [64][576] bf16
    unsigned short* wcbf = wbf + (size_t)64 * 576;             // [2][144][576] bf16
    float* wsC = (float*)(wcbf + (size_t)2 * 144 * 576);       // [144][9216] f32, 5.3 MB
    // ws total ~32.9 MB

    // feat transpose + center passthrough + weight reorders (y==5 slice)
    xprep_kernel<<<dim3(144, 6), 256, 0, stream>>>(x, w_dcn, w_off, xt, wbf, wcbf, out);

    // center-slab conv (frame-invariant, computed once)
    conv_center_kernel<<<288, 576, 0, stream>>>(xt, wcbf, wsC);

    // neighbor-slab conv + wsC + bias -> ofs for 4 frames
    conv_neig_kernel<<<dim3(144, 4), 576, 0, stream>>>(xt, wcbf, b_off, wsC, ofs);

    // deformable sampling + projection
    deform_kernel<<<dim3(288, 4), 256, 0, stream>>>(xt, ofs, wbf, b_dcn, out);
}